// Round 5
// baseline (272.113 us; speedup 1.0000x reference)
//
#include <hip/hip_runtime.h>
#include <cstdint>
#include <cstddef>

typedef unsigned short u16;
typedef unsigned char u8;
typedef __attribute__((ext_vector_type(8))) short bf16x8;
typedef __attribute__((ext_vector_type(4))) float f32x4;
typedef __attribute__((ext_vector_type(4))) int i32x4;
typedef __attribute__((ext_vector_type(8))) int i32x8;

__device__ inline float bf2f(u16 u) { return __uint_as_float(((unsigned)u) << 16); }
__device__ inline unsigned f2bf(float f) {
  unsigned u = __float_as_uint(f);
  u += 0x7fffu + ((u >> 16) & 1u);   // RNE
  return u >> 16;
}

// f32 -> OCP e4m3fn (RNE). Caller guarantees |f| <= 448.
__device__ inline unsigned f2fp8(float f) {
  unsigned s = (__float_as_uint(f) >> 31) << 7;
  float a = fabsf(f);
  if (a >= 0.015625f) {              // normal range
    unsigned u = __float_as_uint(a);
    u += 0x7FFFFu + ((u >> 20) & 1u);
    unsigned e = (u >> 23) - 120u;   // e32 - 127 + 7
    unsigned m = (u >> 20) & 7u;
    return s | (e << 3) | m;
  }
  int m = (int)rintf(a * 512.0f);    // subnormal step 2^-9 (m=8 rolls to min normal)
  return s | (unsigned)m;
}

__device__ inline void async16(const void* g, void* l) {
  __builtin_amdgcn_global_load_lds(
      (const __attribute__((address_space(1))) void*)g,
      (__attribute__((address_space(3))) void*)l, 16, 0, 0);
}

__device__ inline i32x8 join8(i32x4 lo, i32x4 hi) {
  i32x8 r;
  r[0] = lo[0]; r[1] = lo[1]; r[2] = lo[2]; r[3] = lo[3];
  r[4] = hi[0]; r[5] = hi[1]; r[6] = hi[2]; r[7] = hi[3];
  return r;
}

__device__ inline void unpack8(uint4 q, float* o) {
  o[0] = bf2f((u16)(q.x & 0xffffu)); o[1] = bf2f((u16)(q.x >> 16));
  o[2] = bf2f((u16)(q.y & 0xffffu)); o[3] = bf2f((u16)(q.y >> 16));
  o[4] = bf2f((u16)(q.z & 0xffffu)); o[5] = bf2f((u16)(q.z >> 16));
  o[6] = bf2f((u16)(q.w & 0xffffu)); o[7] = bf2f((u16)(q.w >> 16));
}

__device__ inline uint4 pack8(const float* v) {
  uint4 q;
  q.x = f2bf(v[0]) | (f2bf(v[1]) << 16);
  q.y = f2bf(v[2]) | (f2bf(v[3]) << 16);
  q.z = f2bf(v[4]) | (f2bf(v[5]) << 16);
  q.w = f2bf(v[6]) | (f2bf(v[7]) << 16);
  return q;
}

__device__ inline float fast_sigmoid(float z) {
  return 1.0f / (1.0f + exp2f(-1.4426950408889634f * z));
}
__device__ inline float fast_tanh(float z) {
  return 1.0f - 2.0f / (1.0f + exp2f(2.8853900817779268f * z));
}

#define SB0() __builtin_amdgcn_sched_barrier(0)

// ---------------- fused convert: x,h -> bf16+fp8; W_r,U_r -> fp8(x2^13); W_u,U_u,W_c,U_c -> bf16 ----------------
struct ConvArgs2 {
  const float* x; const float* h; const float* wr; const float* ur;
  const float* wbf[4];               // W_u, U_u, W_c, U_c
  u16* xb; u16* hb; u8* x8; u8* h8; u8* w8r; u8* w8u;
  u16* wbo[4];
};

__global__ __launch_bounds__(256) void convert_all(ConvArgs2 a) {
  const int b = blockIdx.x;
  const int t = threadIdx.x;
  if (b < 16384) {
    const bool isx = b < 8192;
    const int off = isx ? b : b - 8192;
    const float* __restrict__ s = isx ? a.x : a.h;
    u16* __restrict__ db = isx ? a.xb : a.hb;
    u8*  __restrict__ d8 = isx ? a.x8 : a.h8;
    const int i = (off * 256 + t) * 4;
    float4 v = *(const float4*)(s + i);
    uint2 o;
    o.x = f2bf(v.x) | (f2bf(v.y) << 16);
    o.y = f2bf(v.z) | (f2bf(v.w) << 16);
    *(uint2*)(db + i) = o;
    unsigned q = f2fp8(v.x) | (f2fp8(v.y) << 8) | (f2fp8(v.z) << 16) | (f2fp8(v.w) << 24);
    *(unsigned*)(d8 + i) = q;
  } else if (b < 18432) {
    const bool isr = b < 17408;
    const int off = isr ? b - 16384 : b - 17408;
    const float* __restrict__ s = isr ? a.wr : a.ur;
    u8* __restrict__ d8 = isr ? a.w8r : a.w8u;
    const int i = (off * 256 + t) * 4;
    float4 v = *(const float4*)(s + i);
    unsigned q = f2fp8(v.x * 8192.f) | (f2fp8(v.y * 8192.f) << 8) |
                 (f2fp8(v.z * 8192.f) << 16) | (f2fp8(v.w * 8192.f) << 24);
    *(unsigned*)(d8 + i) = q;
  } else {
    const int tt = b - 18432;
    const int which = tt >> 10;
    const int off = tt & 1023;
    const float* __restrict__ s = a.wbf[which];
    u16* __restrict__ d = a.wbo[which];
    const int i = (off * 256 + t) * 4;
    float4 v = *(const float4*)(s + i);
    uint2 o;
    o.x = f2bf(v.x) | (f2bf(v.y) << 16);
    o.y = f2bf(v.z) | (f2bf(v.w) << 16);
    *(uint2*)(d + i) = o;
  }
}

// ---------------- fp8 MX GEMM: Y = A @ W^T, 256x256 tile, BK=128, 8-phase, tail-prefetched ds_reads ----------------
struct GemmF8 { const u8* A[2]; const u8* Bw[2]; u16* Y[2]; };

__global__ __launch_bounds__(512, 2) void gemm_fp8(GemmF8 args) {
  const int p = blockIdx.x;                 // 256 blocks, exactly 1/CU
  const int wg = (p & 7) * 32 + (p >> 3);   // XCD-contiguous chunks, bijective (256 % 8 == 0)
  const int gate = wg >> 7;                 // 0..1
  const int rem  = wg & 127;
  const int rblk = rem >> 2;                // 0..31 (256-row panel)
  const int cblk = rem & 3;                 // 0..3  (256-col panel)

  const u8* __restrict__ A  = args.A[gate];
  const u8* __restrict__ Bw = args.Bw[gate];
  u16* __restrict__ Y = args.Y[gate];

  __shared__ __attribute__((aligned(16))) u8 sm[2][2][2][128 * 128];  // 128 KiB

  const int tid  = threadIdx.x;
  const int lane = tid & 63;
  const int w    = tid >> 6;     // 0..7
  const int wm   = w >> 2;       // 0..1 (M half)
  const int wn   = w & 3;        // 0..3 (N quarter)

  const int l8   = lane >> 3;                 // row within 8-row group == row&7
  const int sgrp = (lane & 7) ^ l8;           // pre-swizzled logical col-group (16B units)
  const u8* aSrc = A  + ((size_t)(rblk * 256 + w * 8 + l8) << 10) + sgrp * 16;
  const u8* bSrc = Bw + ((size_t)(cblk * 256 + w * 8 + l8) << 10) + sgrp * 16;
  const int ldsW = w * 8 * 128;               // wave-uniform LDS base (bytes)

  const int sw = lane & 7;
  const int g0 = (lane >> 4) * 2;
  const int o0 = ((g0 ^ sw) << 4);
  const int o1 = (((g0 + 1) ^ sw) << 4);
  const int frR = (lane & 15) * 128;

  f32x4 acc_lo[4][4] = {};   // m 0..3 x n 0..3
  f32x4 acc_hi[4][4] = {};   // m 4..7 x n 0..3

  auto stage = [&](const u8* src, int tt, int op, int half) {
    const int d = tt & 1;
    const u8* s = src + (size_t)half * 131072 + tt * 128;
    u8* l0 = &sm[d][op][half][ldsW];
    async16(s, l0);                       // rows w*8 .. w*8+7
    async16(s + 65536, l0 + 8192);        // rows +64
  };

  // prologue: B0(0) B1(0) A0(0) A1(0) B0(1) B1(1) A0(1)  (14 loads/thread)
  stage(bSrc, 0, 1, 0); stage(bSrc, 0, 1, 1);
  stage(aSrc, 0, 0, 0); stage(aSrc, 0, 0, 1);
  stage(bSrc, 1, 1, 0); stage(bSrc, 1, 1, 1);
  stage(aSrc, 1, 0, 0);
  asm volatile("s_waitcnt vmcnt(6)" ::: "memory");   // tile 0 landed, 3 halves in flight
  __builtin_amdgcn_s_barrier();

  i32x8 alo[4], bfg[4], ahi[4];
  {  // seed tile 0: alo (8 reads), b01 (4), b23 (4)
    const u8* baseA = &sm[0][0][wm][0];
    const u8* baseB = &sm[0][1][wn >> 1][(wn & 1) * 8192];
#pragma unroll
    for (int m = 0; m < 4; ++m) {
      const int ra = frR + m * 2048;
      alo[m] = join8(*(const i32x4*)&baseA[ra + o0], *(const i32x4*)&baseA[ra + o1]);
    }
#pragma unroll
    for (int n = 0; n < 4; ++n) {
      const int rbb = frR + n * 2048;
      bfg[n] = join8(*(const i32x4*)&baseB[rbb + o0], *(const i32x4*)&baseB[rbb + o1]);
    }
  }
  SB0();

  for (int t = 0; t < 8; ++t) {
    const int d = t & 1;
    const u8* baseA  = &sm[d][0][wm][0];
    const u8* baseA2 = &sm[d ^ 1][0][wm][0];
    const u8* baseB2 = &sm[d ^ 1][1][wn >> 1][(wn & 1) * 8192];

    // ---- P0: stage A1(t+1); MFMA lo x n01 ----
    if (t + 1 < 8) stage(aSrc, t + 1, 0, 1);
    SB0();
    __builtin_amdgcn_s_barrier();
    asm volatile("s_waitcnt lgkmcnt(4)" ::: "memory");
    SB0();
    __builtin_amdgcn_s_setprio(1);
#pragma unroll
    for (int m = 0; m < 4; ++m)
#pragma unroll
      for (int n = 0; n < 2; ++n)
        acc_lo[m][n] = __builtin_amdgcn_mfma_scale_f32_16x16x128_f8f6f4(
            alo[m], bfg[n], acc_lo[m][n], 0, 0, 0, 127, 0, 114);
    __builtin_amdgcn_s_setprio(0);
    SB0();
    __builtin_amdgcn_s_barrier();

    // ---- P1: stage B0(t+2); MFMA lo x n23; tail-read A-hi ----
    if (t + 2 < 8) stage(bSrc, t + 2, 1, 0);
    SB0();
    __builtin_amdgcn_s_barrier();
    asm volatile("s_waitcnt lgkmcnt(0)" ::: "memory");
    SB0();
    __builtin_amdgcn_s_setprio(1);
#pragma unroll
    for (int m = 0; m < 4; ++m)
#pragma unroll
      for (int n = 2; n < 4; ++n)
        acc_lo[m][n] = __builtin_amdgcn_mfma_scale_f32_16x16x128_f8f6f4(
            alo[m], bfg[n], acc_lo[m][n], 0, 0, 0, 127, 0, 114);
    __builtin_amdgcn_s_setprio(0);
    SB0();
#pragma unroll
    for (int m = 0; m < 4; ++m) {
      const int ra = frR + m * 2048 + 8192;
      ahi[m] = join8(*(const i32x4*)&baseA[ra + o0], *(const i32x4*)&baseA[ra + o1]);
    }
    SB0();
    __builtin_amdgcn_s_barrier();

    // ---- P2: stage B1(t+2); MFMA hi x n01 ----
    if (t + 2 < 8) stage(bSrc, t + 2, 1, 1);
    SB0();
    __builtin_amdgcn_s_barrier();
    asm volatile("s_waitcnt lgkmcnt(0)" ::: "memory");
    SB0();
    __builtin_amdgcn_s_setprio(1);
#pragma unroll
    for (int m = 0; m < 4; ++m)
#pragma unroll
      for (int n = 0; n < 2; ++n)
        acc_hi[m][n] = __builtin_amdgcn_mfma_scale_f32_16x16x128_f8f6f4(
            ahi[m], bfg[n], acc_hi[m][n], 0, 0, 0, 127, 0, 114);
    __builtin_amdgcn_s_setprio(0);
    SB0();
    __builtin_amdgcn_s_barrier();

    // ---- P3: stage A0(t+2); MFMA hi x n23; vmcnt; tail-read next alo+bfg ----
    if (t + 2 < 8) stage(aSrc, t + 2, 0, 0);
    SB0();
    __builtin_amdgcn_s_barrier();
    __builtin_amdgcn_s_setprio(1);
#pragma unroll
    for (int m = 0; m < 4; ++m)
#pragma unroll
      for (int n = 2; n < 4; ++n)
        acc_hi[m][n] = __builtin_amdgcn_mfma_scale_f32_16x16x128_f8f6f4(
            ahi[m], bfg[n], acc_hi[m][n], 0, 0, 0, 127, 0, 114);
    __builtin_amdgcn_s_setprio(0);
    SB0();
    if (t < 6) asm volatile("s_waitcnt vmcnt(6)" ::: "memory");
    else       asm volatile("s_waitcnt vmcnt(0)" ::: "memory");
    SB0();
    if (t + 1 < 8) {
#pragma unroll
      for (int m = 0; m < 4; ++m) {
        const int ra = frR + m * 2048;
        alo[m] = join8(*(const i32x4*)&baseA2[ra + o0], *(const i32x4*)&baseA2[ra + o1]);
      }
#pragma unroll
      for (int n = 0; n < 4; ++n) {
        const int rbb = frR + n * 2048;
        bfg[n] = join8(*(const i32x4*)&baseB2[rbb + o0], *(const i32x4*)&baseB2[rbb + o1]);
      }
    }
    SB0();
    __builtin_amdgcn_s_barrier();
  }

  const int rBase = rblk * 256 + wm * 128 + (lane >> 4) * 4;
  const int cBase = cblk * 256 + wn * 64 + (lane & 15);
#pragma unroll
  for (int m = 0; m < 4; ++m) {
#pragma unroll
    for (int i = 0; i < 4; ++i) {
      const size_t r0 = (size_t)(rBase + m * 16 + i) * 1024 + cBase;
#pragma unroll
      for (int n = 0; n < 4; ++n) {
        Y[r0 + n * 16]             = (u16)f2bf(acc_lo[m][n][i]);
        Y[r0 + 64 * 1024 + n * 16] = (u16)f2bf(acc_hi[m][n][i]);
      }
    }
  }
}

// ---------------- bf16 NT GEMM: 256x256, BK=64, 8-phase, tail-prefetched; 2 gates, 256 blocks ----------------
// Split from the 4-gate launch for profiler visibility (one full CU-round per launch).
struct Gemm2 { const u16* A[2]; const u16* Bw[2]; u16* Y[2]; };

__global__ __launch_bounds__(512, 2) void gemm_8ph2(Gemm2 args) {
  const int p = blockIdx.x;                 // 256 blocks, exactly 1/CU
  const int wg = (p & 7) * 32 + (p >> 3);   // XCD-contiguous chunks, bijective (256 % 8 == 0)
  const int gate = wg >> 7;                 // 0..1
  const int rem  = wg & 127;
  const int rblk = rem >> 2;                // 0..31 (256-row panel)
  const int cblk = rem & 3;                 // 0..3  (256-col panel)

  const u16* __restrict__ A  = args.A[gate];
  const u16* __restrict__ Bw = args.Bw[gate];
  u16* __restrict__ Y = args.Y[gate];

  __shared__ __attribute__((aligned(16))) u16 sm[2][2][2][128 * 64];  // 128 KiB

  const int tid  = threadIdx.x;
  const int lane = tid & 63;
  const int w    = tid >> 6;     // 0..7
  const int wm   = w >> 2;       // 0..1 (M half of 256)
  const int wn   = w & 3;        // 0..3 (N quarter)

  const int l8   = lane >> 3;                 // row within 8-row group == row&7
  const int sgrp = (lane & 7) ^ l8;           // pre-swizzled logical col-group
  const u16* aSrc = A  + ((size_t)(rblk * 256 + w * 8 + l8) << 10) + sgrp * 8;
  const u16* bSrc = Bw + ((size_t)(cblk * 256 + w * 8 + l8) << 10) + sgrp * 8;
  const int ldsW = w * 8 * 64;                // wave-uniform LDS base (elems)

  const int fr = (lane & 15) * 64 + ((((lane >> 4) ^ (lane & 7))) << 3);

  f32x4 acc_lo[4][4] = {};   // m 0..3  x n 0..3
  f32x4 acc_hi[4][4] = {};   // m 4..7  x n 0..3

  auto stage = [&](const u16* src, int tt, int op, int half) {
    const int d = tt & 1;
    const u16* s = src + (size_t)half * 131072 + tt * 64;
    u16* l0 = &sm[d][op][half][ldsW];
    async16(s, l0);                       // rows w*8 .. w*8+7
    async16(s + 65536, l0 + 4096);        // rows +64
  };

  // prologue: B0(0) B1(0) A0(0) A1(0) B0(1) B1(1) A0(1)  (14 loads/thread)
  stage(bSrc, 0, 1, 0); stage(bSrc, 0, 1, 1);
  stage(aSrc, 0, 0, 0); stage(aSrc, 0, 0, 1);
  stage(bSrc, 1, 1, 0); stage(bSrc, 1, 1, 1);
  stage(aSrc, 1, 0, 0);
  asm volatile("s_waitcnt vmcnt(6)" ::: "memory");   // tile 0 landed, 3 halves in flight
  __builtin_amdgcn_s_barrier();

  bf16x8 alo[2][4], bfg[2][4], ahi[2][4];
  {  // seed tile 0
    const u16* baseA = &sm[0][0][wm][0];
    const u16* baseB = &sm[0][1][wn >> 1][(wn & 1) * 4096];
#pragma unroll
    for (int kk = 0; kk < 2; ++kk) {
      const int fo = fr ^ (kk << 5);
#pragma unroll
      for (int m = 0; m < 4; ++m) alo[kk][m] = *(const bf16x8*)(baseA + m * 1024 + fo);
    }
#pragma unroll
    for (int n = 0; n < 4; ++n)
#pragma unroll
      for (int kk = 0; kk < 2; ++kk)
        bfg[kk][n] = *(const bf16x8*)(baseB + n * 1024 + (fr ^ (kk << 5)));
  }
  SB0();

  for (int t = 0; t < 16; ++t) {
    const int d = t & 1;
    const u16* baseA  = &sm[d][0][wm][0];
    const u16* baseA2 = &sm[d ^ 1][0][wm][0];
    const u16* baseB2 = &sm[d ^ 1][1][wn >> 1][(wn & 1) * 4096];

    // ---- P0: stage A1(t+1); MFMA lo x n01 ----
    if (t + 1 < 16) stage(aSrc, t + 1, 0, 1);
    SB0();
    __builtin_amdgcn_s_barrier();
    asm volatile("s_waitcnt lgkmcnt(4)" ::: "memory");
    SB0();
    __builtin_amdgcn_s_setprio(1);
#pragma unroll
    for (int m = 0; m < 4; ++m)
#pragma unroll
      for (int n = 0; n < 2; ++n)
#pragma unroll
        for (int kk = 0; kk < 2; ++kk)
          acc_lo[m][n] = __builtin_amdgcn_mfma_f32_16x16x32_bf16(alo[kk][m], bfg[kk][n], acc_lo[m][n], 0, 0, 0);
    __builtin_amdgcn_s_setprio(0);
    SB0();
    __builtin_amdgcn_s_barrier();

    // ---- P1: stage B0(t+2); MFMA lo x n23; tail-read A-hi ----
    if (t + 2 < 16) stage(bSrc, t + 2, 1, 0);
    SB0();
    __builtin_amdgcn_s_barrier();
    asm volatile("s_waitcnt lgkmcnt(0)" ::: "memory");
    SB0();
    __builtin_amdgcn_s_setprio(1);
#pragma unroll
    for (int m = 0; m < 4; ++m)
#pragma unroll
      for (int n = 2; n < 4; ++n)
#pragma unroll
        for (int kk = 0; kk < 2; ++kk)
          acc_lo[m][n] = __builtin_amdgcn_mfma_f32_16x16x32_bf16(alo[kk][m], bfg[kk][n], acc_lo[m][n], 0, 0, 0);
    __builtin_amdgcn_s_setprio(0);
    SB0();
#pragma unroll
    for (int kk = 0; kk < 2; ++kk) {
      const int fo = fr ^ (kk << 5);
#pragma unroll
      for (int m = 0; m < 4; ++m) ahi[kk][m] = *(const bf16x8*)(baseA + (m + 4) * 1024 + fo);
    }
    SB0();
    __builtin_amdgcn_s_barrier();

    // ---- P2: stage B1(t+2); MFMA hi x n01 ----
    if (t + 2 < 16) stage(bSrc, t + 2, 1, 1);
    SB0();
    __builtin_amdgcn_s_barrier();
    asm volatile("s_waitcnt lgkmcnt(0)" ::: "memory");
    SB0();
    __builtin_amdgcn_s_setprio(1);
#pragma unroll
    for (int m = 0; m < 4; ++m)
#pragma unroll
      for (int n = 0; n < 2; ++n)
#pragma unroll
        for (int kk = 0; kk < 2; ++kk)
          acc_hi[m][n] = __builtin_amdgcn_mfma_f32_16x16x32_bf16(ahi[kk][m], bfg[kk][n], acc_hi[m][n], 0, 0, 0);
    __builtin_amdgcn_s_setprio(0);
    SB0();
    __builtin_amdgcn_s_barrier();

    // ---- P3: stage A0(t+2); MFMA hi x n23; vmcnt; tail-read next alo+bfg ----
    if (t + 2 < 16) stage(aSrc, t + 2, 0, 0);
    SB0();
    __builtin_amdgcn_s_barrier();
    __builtin_amdgcn_s_setprio(1);
#pragma unroll
    for (int m = 0; m < 4; ++m)
#pragma unroll
      for (int n = 2; n < 4; ++n)
#pragma unroll
        for (int kk = 0; kk < 2; ++kk)
          acc_hi[m][n] = __builtin_amdgcn_mfma_f32_16x16x32_bf16(ahi[kk][m], bfg[kk][n], acc_hi[m][n], 0, 0, 0);
    __builtin_amdgcn_s_setprio(0);
    SB0();
    if (t < 14) asm volatile("s_waitcnt vmcnt(6)" ::: "memory");
    else        asm volatile("s_waitcnt vmcnt(0)" ::: "memory");
    SB0();
    if (t + 1 < 16) {
#pragma unroll
      for (int kk = 0; kk < 2; ++kk) {
        const int fo = fr ^ (kk << 5);
#pragma unroll
        for (int m = 0; m < 4; ++m) alo[kk][m] = *(const bf16x8*)(baseA2 + m * 1024 + fo);
      }
#pragma unroll
      for (int n = 0; n < 4; ++n)
#pragma unroll
        for (int kk = 0; kk < 2; ++kk)
          bfg[kk][n] = *(const bf16x8*)(baseB2 + n * 1024 + (fr ^ (kk << 5)));
    }
    SB0();
    __builtin_amdgcn_s_barrier();
  }

  const int rBase = rblk * 256 + wm * 128 + (lane >> 4) * 4;
  const int cBase = cblk * 256 + wn * 64 + (lane & 15);
#pragma unroll
  for (int m = 0; m < 4; ++m) {
#pragma unroll
    for (int i = 0; i < 4; ++i) {
      const size_t r0 = (size_t)(rBase + m * 16 + i) * 1024 + cBase;
#pragma unroll
      for (int n = 0; n < 4; ++n) {
        Y[r0 + n * 16]             = (u16)f2bf(acc_lo[m][n][i]);
        Y[r0 + 64 * 1024 + n * 16] = (u16)f2bf(acc_hi[m][n][i]);
      }
    }
  }
}

// ---------------- r gate: wave-per-row, no barriers ----------------
__global__ __launch_bounds__(256) void rgate_kernel(
    const u16* __restrict__ Yrh, const u16* __restrict__ Yrx,
    const u16* __restrict__ hb, const float* __restrict__ gamma,
    const float* __restrict__ beta, u16* __restrict__ hrb) {
  const int row  = blockIdx.x * 4 + (threadIdx.x >> 6);
  const int lane = threadIdx.x & 63;
  const size_t rb = (size_t)row * 1024;

  uint4 qa[2], qb[2], qh[2];
  qa[0] = *(const uint4*)(Yrh + rb + lane * 8);
  qa[1] = *(const uint4*)(Yrh + rb + 512 + lane * 8);
  qb[0] = *(const uint4*)(Yrx + rb + lane * 8);
  qb[1] = *(const uint4*)(Yrx + rb + 512 + lane * 8);
  qh[0] = *(const uint4*)(hb  + rb + lane * 8);
  qh[1] = *(const uint4*)(hb  + rb + 512 + lane * 8);

  float s0 = 0.f, s0q = 0.f, s1 = 0.f, s1q = 0.f;
  float tmp[8];
#pragma unroll
  for (int c = 0; c < 2; c++) {
    unpack8(qa[c], tmp);
#pragma unroll
    for (int j = 0; j < 8; j++) { s0 += tmp[j]; s0q += tmp[j] * tmp[j]; }
    unpack8(qb[c], tmp);
#pragma unroll
    for (int j = 0; j < 8; j++) { s1 += tmp[j]; s1q += tmp[j] * tmp[j]; }
  }
#pragma unroll
  for (int off = 1; off < 64; off <<= 1) {
    s0 += __shfl_xor(s0, off, 64);  s0q += __shfl_xor(s0q, off, 64);
    s1 += __shfl_xor(s1, off, 64);  s1q += __shfl_xor(s1q, off, 64);
  }

  const float inv = 1.0f / 1024.0f;
  const float mu0 = s0 * inv, rs0 = rsqrtf(s0q * inv - mu0 * mu0 + 1e-5f);
  const float mu1 = s1 * inv, rs1 = rsqrtf(s1q * inv - mu1 * mu1 + 1e-5f);

#pragma unroll
  for (int c = 0; c < 2; c++) {
    const int cb = c * 512 + lane * 8;
    float va[8], vb[8], vh[8], o[8];
    unpack8(qa[c], va); unpack8(qb[c], vb); unpack8(qh[c], vh);
#pragma unroll
    for (int j = 0; j < 8; j++) {
      const float ln0 = (va[j] - mu0) * rs0 * gamma[cb + j] + beta[cb + j];
      const float ln1 = (vb[j] - mu1) * rs1 * gamma[1024 + cb + j] + beta[1024 + cb + j];
      const float rg = fast_sigmoid(ln0 + ln1);
      o[j] = vh[j] * rg;
    }
    *(uint4*)(hrb + rb + cb) = pack8(o);  // aliases Yrx: per-thread read-before-write
  }
}

// ---------------- final: wave-per-row, h read in fp32 ----------------
__global__ __launch_bounds__(256) void final_fuse(
    const u16* __restrict__ Yuh, const u16* __restrict__ Yux,
    const u16* __restrict__ Ych, const u16* __restrict__ Ycx,
    const float* __restrict__ h, const float* __restrict__ gamma,
    const float* __restrict__ beta, float* __restrict__ out) {
  const int row  = blockIdx.x * 4 + (threadIdx.x >> 6);
  const int lane = threadIdx.x & 63;
  const size_t rb = (size_t)row * 1024;

  uint4 q0[2], q1[2], q2[2], q3[2];
  float4 hf[4];
#pragma unroll
  for (int c = 0; c < 2; c++) {
    const int cb = c * 512 + lane * 8;
    q0[c] = *(const uint4*)(Yuh + rb + cb);
    q1[c] = *(const uint4*)(Yux + rb + cb);
    q2[c] = *(const uint4*)(Ych + rb + cb);
    q3[c] = *(const uint4*)(Ycx + rb + cb);
    hf[c * 2]     = *(const float4*)(h + rb + cb);
    hf[c * 2 + 1] = *(const float4*)(h + rb + cb + 4);
  }

  float s[8] = {0.f, 0.f, 0.f, 0.f, 0.f, 0.f, 0.f, 0.f};
  float tmp[8];
#pragma unroll
  for (int c = 0; c < 2; c++) {
    unpack8(q0[c], tmp);
#pragma unroll
    for (int j = 0; j < 8; j++) { s[0] += tmp[j]; s[1] += tmp[j] * tmp[j]; }
    unpack8(q1[c], tmp);
#pragma unroll
    for (int j = 0; j < 8; j++) { s[2] += tmp[j]; s[3] += tmp[j] * tmp[j]; }
    unpack8(q2[c], tmp);
#pragma unroll
    for (int j = 0; j < 8; j++) { s[4] += tmp[j]; s[5] += tmp[j] * tmp[j]; }
    unpack8(q3[c], tmp);
#pragma unroll
    for (int j = 0; j < 8; j++) { s[6] += tmp[j]; s[7] += tmp[j] * tmp[j]; }
  }
#pragma unroll
  for (int off = 1; off < 64; off <<= 1) {
#pragma unroll
    for (int q = 0; q < 8; q++) s[q] += __shfl_xor(s[q], off, 64);
  }

  const float inv = 1.0f / 1024.0f;
  const float mu0 = s[0] * inv, rs0 = rsqrtf(s[1] * inv - mu0 * mu0 + 1e-5f);
  const float mu1 = s[2] * inv, rs1 = rsqrtf(s[3] * inv - mu1 * mu1 + 1e-5f);
  const float mu2 = s[4] * inv, rs2 = rsqrtf(s[5] * inv - mu2 * mu2 + 1e-5f);
  const float mu3 = s[6] * inv, rs3 = rsqrtf(s[7] * inv - mu3 * mu3 + 1e-5f);

#pragma unroll
  for (int c = 0; c < 2; c++) {
    const int cb = c * 512 + lane * 8;
    float v0[8], v1[8], v2[8], v3[8];
    unpack8(q0[c], v0); unpack8(q1[c], v1); unpack8(q2[c], v2); unpack8(q3[c], v3);
    const float* hv = (const float*)&hf[c * 2];
    float o[8];
#pragma unroll
    for (int j = 0; j < 8; j++) {
      const int cc = cb + j;
      const float ln2 = (v0[j] - mu0) * rs0 * gamma[2 * 1024 + cc] + beta[2 * 1024 + cc];
      const float ln3 = (v1[j] - mu1) * rs1 * gamma[3 * 1024 + cc] + beta[3 * 1024 + cc];
      const float ln4 = (v2[j] - mu2) * rs2 * gamma[4 * 1024 + cc] + beta[4 * 1024 + cc];
      const float ln5 = (v3[j] - mu3) * rs3 * gamma[5 * 1024 + cc] + beta[5 * 1024 + cc];
      const float u  = fast_sigmoid(ln2 + ln3);
      const float cg = fast_tanh(ln4 + ln5);
      o[j] = (1.0f - u) * hv[j] + u * cg;
    }
    *(float4*)(out + rb + cb)     = *(float4*)&o[0];
    *(float4*)(out + rb + cb + 4) = *(float4*)&o[4];
  }
}

extern "C" void kernel_launch(void* const* d_in, const int* in_sizes, int n_in,
                              void* d_out, int out_size, void* d_ws, size_t ws_size,
                              hipStream_t stream) {
  const float* x  = (const float*)d_in[0];
  const float* h  = (const float*)d_in[1];
  const float* W_r = (const float*)d_in[2];
  const float* U_r = (const float*)d_in[3];
  const float* W_u = (const float*)d_in[4];
  const float* U_u = (const float*)d_in[5];
  const float* W_c = (const float*)d_in[6];
  const float* U_c = (const float*)d_in[7];
  const float* gamma = (const float*)d_in[8];
  const float* beta  = (const float*)d_in[9];
  float* out = (float*)d_out;

  char* ws = (char*)d_ws;
  const size_t MB = 1024 * 1024;
  const size_t SZ_ACT = 16 * MB;     // 8192x1024 bf16

  u16* xb = (u16*)(ws);                       // 16 MiB
  u16* hb = (u16*)(ws + 16 * MB);             // 16 MiB
  u16* wb[4];                                 // bf16 weights: W_u, U_u, W_c, U_c
  for (int i = 0; i < 4; i++) wb[i] = (u16*)(ws + (32 + 2 * i) * MB);
  u8* w8r = (u8*)(ws + 40 * MB);              // W_r fp8 (1 MiB)
  u8* w8u = (u8*)(ws + 41 * MB);              // U_r fp8 (1 MiB)
  char* ybase = ws + 42 * MB;
  u16* Y0 = (u16*)(ybase);                    // r_hidden; reused for c_hidden out
  u16* Y1 = (u16*)(ybase + SZ_ACT);           // r_input;  reused for hr
  u16* Y2 = (u16*)(ybase + 2 * SZ_ACT);       // u_hidden
  u16* Y3 = (u16*)(ybase + 3 * SZ_ACT);       // u_input
  u16* Y5 = (u16*)(ybase + 4 * SZ_ACT);       // c_input (written in step 3b)
  u8* x8 = (u8*)Y5;                           // fp8 x, aliased into Y5 (dead after step 2)
  u8* h8 = (u8*)Y5 + 8 * MB;                  // fp8 h
  // total ws: 42 + 80 = 122 MiB

  // 1) fused convert
  ConvArgs2 ca = {};
  ca.x = x; ca.h = h; ca.wr = W_r; ca.ur = U_r;
  ca.wbf[0] = W_u; ca.wbf[1] = U_u; ca.wbf[2] = W_c; ca.wbf[3] = U_c;
  ca.xb = xb; ca.hb = hb; ca.x8 = x8; ca.h8 = h8; ca.w8r = w8r; ca.w8u = w8u;
  ca.wbo[0] = (u16*)(ws + 32 * MB); ca.wbo[1] = (u16*)(ws + 34 * MB);
  ca.wbo[2] = (u16*)(ws + 36 * MB); ca.wbo[3] = (u16*)(ws + 38 * MB);
  convert_all<<<22528, 256, 0, stream>>>(ca);

  // 2) fp8 MX GEMMs: r_h = h@W_r^T -> Y0, r_x = x@U_r^T -> Y1  (256 blocks x 512 thr)
  GemmF8 gf = {};
  gf.A[0] = h8; gf.Bw[0] = w8r; gf.Y[0] = Y0;
  gf.A[1] = x8; gf.Bw[1] = w8u; gf.Y[1] = Y1;
  gemm_fp8<<<256, 512, 0, stream>>>(gf);

  // 3a) bf16 x-side GEMMs: u_x -> Y3, c_x -> Y5  (Y5/x8 alias: fp8 inputs dead after step 2)
  Gemm2 ga = {};
  ga.A[0] = xb; ga.Bw[0] = wb[1]; ga.Y[0] = Y3;   // u_x = x@U_u^T
  ga.A[1] = xb; ga.Bw[1] = wb[3]; ga.Y[1] = Y5;   // c_x = x@U_c^T
  gemm_8ph2<<<256, 512, 0, stream>>>(ga);

  // 4) r gate + hr (hr overwrites Y1; per-thread read-before-write)
  rgate_kernel<<<2048, 256, 0, stream>>>(Y0, Y1, hb, gamma, beta, Y1);

  // 3b) bf16 h-side GEMMs: u_h -> Y2, c_h -> Y0
  Gemm2 gbb = {};
  gbb.A[0] = hb; gbb.Bw[0] = wb[0]; gbb.Y[0] = Y2;   // u_h = h@W_u^T
  gbb.A[1] = Y1; gbb.Bw[1] = wb[2]; gbb.Y[1] = Y0;   // c_h = hr@W_c^T
  gemm_8ph2<<<256, 512, 0, stream>>>(gbb);

  // 5) u, c, out (h in fp32)
  final_fuse<<<2048, 256, 0, stream>>>(Y2, Y3, Y0, Y5, h, gamma, beta, out);
}

// Round 6
// 241.965 us; speedup vs baseline: 1.1246x; 1.1246x over previous
//
#include <hip/hip_runtime.h>
#include <cstdint>
#include <cstddef>

typedef unsigned short u16;
typedef unsigned char u8;
typedef __attribute__((ext_vector_type(4))) float f32x4;
typedef __attribute__((ext_vector_type(4))) int i32x4;
typedef __attribute__((ext_vector_type(8))) int i32x8;

__device__ inline float bf2f(u16 u) { return __uint_as_float(((unsigned)u) << 16); }
__device__ inline unsigned f2bf(float f) {
  unsigned u = __float_as_uint(f);
  u += 0x7fffu + ((u >> 16) & 1u);   // RNE
  return u >> 16;
}

// f32 -> OCP e4m3fn (RNE). Caller guarantees |f| <= 448.
__device__ inline unsigned f2fp8(float f) {
  unsigned s = (__float_as_uint(f) >> 31) << 7;
  float a = fabsf(f);
  if (a >= 0.015625f) {              // normal range
    unsigned u = __float_as_uint(a);
    u += 0x7FFFFu + ((u >> 20) & 1u);
    unsigned e = (u >> 23) - 120u;   // e32 - 127 + 7
    unsigned m = (u >> 20) & 7u;
    return s | (e << 3) | m;
  }
  int m = (int)rintf(a * 512.0f);    // subnormal step 2^-9 (m=8 rolls to min normal)
  return s | (unsigned)m;
}

__device__ inline void async16(const void* g, void* l) {
  __builtin_amdgcn_global_load_lds(
      (const __attribute__((address_space(1))) void*)g,
      (__attribute__((address_space(3))) void*)l, 16, 0, 0);
}

__device__ inline i32x8 join8(i32x4 lo, i32x4 hi) {
  i32x8 r;
  r[0] = lo[0]; r[1] = lo[1]; r[2] = lo[2]; r[3] = lo[3];
  r[4] = hi[0]; r[5] = hi[1]; r[6] = hi[2]; r[7] = hi[3];
  return r;
}

__device__ inline void unpack8(uint4 q, float* o) {
  o[0] = bf2f((u16)(q.x & 0xffffu)); o[1] = bf2f((u16)(q.x >> 16));
  o[2] = bf2f((u16)(q.y & 0xffffu)); o[3] = bf2f((u16)(q.y >> 16));
  o[4] = bf2f((u16)(q.z & 0xffffu)); o[5] = bf2f((u16)(q.z >> 16));
  o[6] = bf2f((u16)(q.w & 0xffffu)); o[7] = bf2f((u16)(q.w >> 16));
}

__device__ inline float fast_sigmoid(float z) {
  return 1.0f / (1.0f + exp2f(-1.4426950408889634f * z));
}
__device__ inline float fast_tanh(float z) {
  return 1.0f - 2.0f / (1.0f + exp2f(2.8853900817779268f * z));
}

#define SB0() __builtin_amdgcn_sched_barrier(0)

// ---------------- fused convert: x,h -> fp8; all 6 weights -> fp8(x2^13) ----------------
struct ConvArgs3 {
  const float* x; const float* h;
  const float* w[6];                 // W_r, U_r, W_u, U_u, W_c, U_c
  u8* x8; u8* h8;
  u8* w8[6];
};

__global__ __launch_bounds__(256) void convert_all(ConvArgs3 a) {
  const int b = blockIdx.x;
  const int t = threadIdx.x;
  if (b < 16384) {
    const bool isx = b < 8192;
    const int off = isx ? b : b - 8192;
    const float* __restrict__ s = isx ? a.x : a.h;
    u8* __restrict__ d8 = isx ? a.x8 : a.h8;
    const int i = (off * 256 + t) * 4;
    float4 v = *(const float4*)(s + i);
    unsigned q = f2fp8(v.x) | (f2fp8(v.y) << 8) | (f2fp8(v.z) << 16) | (f2fp8(v.w) << 24);
    *(unsigned*)(d8 + i) = q;
  } else {
    const int tt = b - 16384;
    const int which = tt >> 10;      // 0..5
    const int off = tt & 1023;
    const float* __restrict__ s = a.w[which];
    u8* __restrict__ d8 = a.w8[which];
    const int i = (off * 256 + t) * 4;
    float4 v = *(const float4*)(s + i);
    unsigned q = f2fp8(v.x * 8192.f) | (f2fp8(v.y * 8192.f) << 8) |
                 (f2fp8(v.z * 8192.f) << 16) | (f2fp8(v.w * 8192.f) << 24);
    *(unsigned*)(d8 + i) = q;
  }
}

// ---------------- fp8 MX GEMM: Y = A @ W^T, 256x256 tile, BK=128, 8-phase, tail-prefetched ----------------
// Verified schedule (R2/R4 passing). NG gates x 128 blocks each; grid = NG*128 (multiple of 8).
// LDS sm[dbuf][op][half] 128 rows x 128 B fp8, XOR swizzle phys kgroup = logical ^ (row&7).
// vmcnt(6) once per K-tile; never 0 mid-loop. Scales: A = 2^0 (127), W x2^13 -> 2^-13 (114).
struct GemmF8 { const u8* A[4]; const u8* Bw[4]; u16* Y[4]; };

template <int NG>
__global__ __launch_bounds__(512, 2) void gemm_fp8(GemmF8 args) {
  const int p = blockIdx.x;                       // NG*128 blocks
  const int wg = (p & 7) * (NG * 16) + (p >> 3);  // XCD-contiguous, bijective
  const int gate = wg >> 7;                       // 0..NG-1
  const int rem  = wg & 127;
  const int rblk = rem >> 2;                      // 0..31 (256-row panel)
  const int cblk = rem & 3;                       // 0..3  (256-col panel)

  const u8* __restrict__ A  = args.A[gate];
  const u8* __restrict__ Bw = args.Bw[gate];
  u16* __restrict__ Y = args.Y[gate];

  __shared__ __attribute__((aligned(16))) u8 sm[2][2][2][128 * 128];  // 128 KiB

  const int tid  = threadIdx.x;
  const int lane = tid & 63;
  const int w    = tid >> 6;     // 0..7
  const int wm   = w >> 2;       // 0..1 (M half)
  const int wn   = w & 3;        // 0..3 (N quarter)

  const int l8   = lane >> 3;                 // row within 8-row group == row&7
  const int sgrp = (lane & 7) ^ l8;           // pre-swizzled logical col-group (16B units)
  const u8* aSrc = A  + ((size_t)(rblk * 256 + w * 8 + l8) << 10) + sgrp * 16;
  const u8* bSrc = Bw + ((size_t)(cblk * 256 + w * 8 + l8) << 10) + sgrp * 16;
  const int ldsW = w * 8 * 128;               // wave-uniform LDS base (bytes)

  const int sw = lane & 7;
  const int g0 = (lane >> 4) * 2;
  const int o0 = ((g0 ^ sw) << 4);
  const int o1 = (((g0 + 1) ^ sw) << 4);
  const int frR = (lane & 15) * 128;

  f32x4 acc_lo[4][4] = {};   // m 0..3 x n 0..3
  f32x4 acc_hi[4][4] = {};   // m 4..7 x n 0..3

  auto stage = [&](const u8* src, int tt, int op, int half) {
    const int d = tt & 1;
    const u8* s = src + (size_t)half * 131072 + tt * 128;
    u8* l0 = &sm[d][op][half][ldsW];
    async16(s, l0);                       // rows w*8 .. w*8+7
    async16(s + 65536, l0 + 8192);        // rows +64
  };

  // prologue: B0(0) B1(0) A0(0) A1(0) B0(1) B1(1) A0(1)  (14 loads/thread)
  stage(bSrc, 0, 1, 0); stage(bSrc, 0, 1, 1);
  stage(aSrc, 0, 0, 0); stage(aSrc, 0, 0, 1);
  stage(bSrc, 1, 1, 0); stage(bSrc, 1, 1, 1);
  stage(aSrc, 1, 0, 0);
  asm volatile("s_waitcnt vmcnt(6)" ::: "memory");   // tile 0 landed, 3 halves in flight
  __builtin_amdgcn_s_barrier();

  i32x8 alo[4], bfg[4], ahi[4];
  {  // seed tile 0: alo (8 reads), b01 (4), b23 (4)
    const u8* baseA = &sm[0][0][wm][0];
    const u8* baseB = &sm[0][1][wn >> 1][(wn & 1) * 8192];
#pragma unroll
    for (int m = 0; m < 4; ++m) {
      const int ra = frR + m * 2048;
      alo[m] = join8(*(const i32x4*)&baseA[ra + o0], *(const i32x4*)&baseA[ra + o1]);
    }
#pragma unroll
    for (int n = 0; n < 4; ++n) {
      const int rbb = frR + n * 2048;
      bfg[n] = join8(*(const i32x4*)&baseB[rbb + o0], *(const i32x4*)&baseB[rbb + o1]);
    }
  }
  SB0();

  for (int t = 0; t < 8; ++t) {
    const int d = t & 1;
    const u8* baseA  = &sm[d][0][wm][0];
    const u8* baseA2 = &sm[d ^ 1][0][wm][0];
    const u8* baseB2 = &sm[d ^ 1][1][wn >> 1][(wn & 1) * 8192];

    // ---- P0: stage A1(t+1); MFMA lo x n01 ----
    if (t + 1 < 8) stage(aSrc, t + 1, 0, 1);
    SB0();
    __builtin_amdgcn_s_barrier();
    asm volatile("s_waitcnt lgkmcnt(4)" ::: "memory");
    SB0();
    __builtin_amdgcn_s_setprio(1);
#pragma unroll
    for (int m = 0; m < 4; ++m)
#pragma unroll
      for (int n = 0; n < 2; ++n)
        acc_lo[m][n] = __builtin_amdgcn_mfma_scale_f32_16x16x128_f8f6f4(
            alo[m], bfg[n], acc_lo[m][n], 0, 0, 0, 127, 0, 114);
    __builtin_amdgcn_s_setprio(0);
    SB0();
    __builtin_amdgcn_s_barrier();

    // ---- P1: stage B0(t+2); MFMA lo x n23; tail-read A-hi ----
    if (t + 2 < 8) stage(bSrc, t + 2, 1, 0);
    SB0();
    __builtin_amdgcn_s_barrier();
    asm volatile("s_waitcnt lgkmcnt(0)" ::: "memory");
    SB0();
    __builtin_amdgcn_s_setprio(1);
#pragma unroll
    for (int m = 0; m < 4; ++m)
#pragma unroll
      for (int n = 2; n < 4; ++n)
        acc_lo[m][n] = __builtin_amdgcn_mfma_scale_f32_16x16x128_f8f6f4(
            alo[m], bfg[n], acc_lo[m][n], 0, 0, 0, 127, 0, 114);
    __builtin_amdgcn_s_setprio(0);
    SB0();
#pragma unroll
    for (int m = 0; m < 4; ++m) {
      const int ra = frR + m * 2048 + 8192;
      ahi[m] = join8(*(const i32x4*)&baseA[ra + o0], *(const i32x4*)&baseA[ra + o1]);
    }
    SB0();
    __builtin_amdgcn_s_barrier();

    // ---- P2: stage B1(t+2); MFMA hi x n01 ----
    if (t + 2 < 8) stage(bSrc, t + 2, 1, 1);
    SB0();
    __builtin_amdgcn_s_barrier();
    asm volatile("s_waitcnt lgkmcnt(0)" ::: "memory");
    SB0();
    __builtin_amdgcn_s_setprio(1);
#pragma unroll
    for (int m = 0; m < 4; ++m)
#pragma unroll
      for (int n = 0; n < 2; ++n)
        acc_hi[m][n] = __builtin_amdgcn_mfma_scale_f32_16x16x128_f8f6f4(
            ahi[m], bfg[n], acc_hi[m][n], 0, 0, 0, 127, 0, 114);
    __builtin_amdgcn_s_setprio(0);
    SB0();
    __builtin_amdgcn_s_barrier();

    // ---- P3: stage A0(t+2); MFMA hi x n23; vmcnt; tail-read next alo+bfg ----
    if (t + 2 < 8) stage(aSrc, t + 2, 0, 0);
    SB0();
    __builtin_amdgcn_s_barrier();
    __builtin_amdgcn_s_setprio(1);
#pragma unroll
    for (int m = 0; m < 4; ++m)
#pragma unroll
      for (int n = 2; n < 4; ++n)
        acc_hi[m][n] = __builtin_amdgcn_mfma_scale_f32_16x16x128_f8f6f4(
            ahi[m], bfg[n], acc_hi[m][n], 0, 0, 0, 127, 0, 114);
    __builtin_amdgcn_s_setprio(0);
    SB0();
    if (t < 6) asm volatile("s_waitcnt vmcnt(6)" ::: "memory");
    else       asm volatile("s_waitcnt vmcnt(0)" ::: "memory");
    SB0();
    if (t + 1 < 8) {
#pragma unroll
      for (int m = 0; m < 4; ++m) {
        const int ra = frR + m * 2048;
        alo[m] = join8(*(const i32x4*)&baseA2[ra + o0], *(const i32x4*)&baseA2[ra + o1]);
      }
#pragma unroll
      for (int n = 0; n < 4; ++n) {
        const int rbb = frR + n * 2048;
        bfg[n] = join8(*(const i32x4*)&baseB2[rbb + o0], *(const i32x4*)&baseB2[rbb + o1]);
      }
    }
    SB0();
    __builtin_amdgcn_s_barrier();
  }

  const int rBase = rblk * 256 + wm * 128 + (lane >> 4) * 4;
  const int cBase = cblk * 256 + wn * 64 + (lane & 15);
#pragma unroll
  for (int m = 0; m < 4; ++m) {
#pragma unroll
    for (int i = 0; i < 4; ++i) {
      const size_t r0 = (size_t)(rBase + m * 16 + i) * 1024 + cBase;
#pragma unroll
      for (int n = 0; n < 4; ++n) {
        Y[r0 + n * 16]             = (u16)f2bf(acc_lo[m][n][i]);
        Y[r0 + 64 * 1024 + n * 16] = (u16)f2bf(acc_hi[m][n][i]);
      }
    }
  }
}

// ---------------- r gate: wave-per-row; reads h fp32; writes hr as fp8 ----------------
__global__ __launch_bounds__(256) void rgate_kernel(
    const u16* __restrict__ Yrh, const u16* __restrict__ Yrx,
    const float* __restrict__ h, const float* __restrict__ gamma,
    const float* __restrict__ beta, u8* __restrict__ hr8) {
  const int row  = blockIdx.x * 4 + (threadIdx.x >> 6);
  const int lane = threadIdx.x & 63;
  const size_t rb = (size_t)row * 1024;

  uint4 qa[2], qb[2];
  float4 hf[4];
#pragma unroll
  for (int c = 0; c < 2; c++) {
    const int cb = c * 512 + lane * 8;
    qa[c] = *(const uint4*)(Yrh + rb + cb);
    qb[c] = *(const uint4*)(Yrx + rb + cb);
    hf[c * 2]     = *(const float4*)(h + rb + cb);
    hf[c * 2 + 1] = *(const float4*)(h + rb + cb + 4);
  }

  float s0 = 0.f, s0q = 0.f, s1 = 0.f, s1q = 0.f;
  float tmp[8];
#pragma unroll
  for (int c = 0; c < 2; c++) {
    unpack8(qa[c], tmp);
#pragma unroll
    for (int j = 0; j < 8; j++) { s0 += tmp[j]; s0q += tmp[j] * tmp[j]; }
    unpack8(qb[c], tmp);
#pragma unroll
    for (int j = 0; j < 8; j++) { s1 += tmp[j]; s1q += tmp[j] * tmp[j]; }
  }
#pragma unroll
  for (int off = 1; off < 64; off <<= 1) {
    s0 += __shfl_xor(s0, off, 64);  s0q += __shfl_xor(s0q, off, 64);
    s1 += __shfl_xor(s1, off, 64);  s1q += __shfl_xor(s1q, off, 64);
  }

  const float inv = 1.0f / 1024.0f;
  const float mu0 = s0 * inv, rs0 = rsqrtf(s0q * inv - mu0 * mu0 + 1e-5f);
  const float mu1 = s1 * inv, rs1 = rsqrtf(s1q * inv - mu1 * mu1 + 1e-5f);

#pragma unroll
  for (int c = 0; c < 2; c++) {
    const int cb = c * 512 + lane * 8;
    float va[8], vb[8], o[8];
    unpack8(qa[c], va); unpack8(qb[c], vb);
    const float* hv = (const float*)&hf[c * 2];
#pragma unroll
    for (int j = 0; j < 8; j++) {
      const float ln0 = (va[j] - mu0) * rs0 * gamma[cb + j] + beta[cb + j];
      const float ln1 = (vb[j] - mu1) * rs1 * gamma[1024 + cb + j] + beta[1024 + cb + j];
      const float rg = fast_sigmoid(ln0 + ln1);
      o[j] = hv[j] * rg;
    }
    uint2 q;
    q.x = f2fp8(o[0]) | (f2fp8(o[1]) << 8) | (f2fp8(o[2]) << 16) | (f2fp8(o[3]) << 24);
    q.y = f2fp8(o[4]) | (f2fp8(o[5]) << 8) | (f2fp8(o[6]) << 16) | (f2fp8(o[7]) << 24);
    *(uint2*)(hr8 + rb + cb) = q;
  }
}

// ---------------- final: wave-per-row, h read in fp32 ----------------
__global__ __launch_bounds__(256) void final_fuse(
    const u16* __restrict__ Yuh, const u16* __restrict__ Yux,
    const u16* __restrict__ Ych, const u16* __restrict__ Ycx,
    const float* __restrict__ h, const float* __restrict__ gamma,
    const float* __restrict__ beta, float* __restrict__ out) {
  const int row  = blockIdx.x * 4 + (threadIdx.x >> 6);
  const int lane = threadIdx.x & 63;
  const size_t rb = (size_t)row * 1024;

  uint4 q0[2], q1[2], q2[2], q3[2];
  float4 hf[4];
#pragma unroll
  for (int c = 0; c < 2; c++) {
    const int cb = c * 512 + lane * 8;
    q0[c] = *(const uint4*)(Yuh + rb + cb);
    q1[c] = *(const uint4*)(Yux + rb + cb);
    q2[c] = *(const uint4*)(Ych + rb + cb);
    q3[c] = *(const uint4*)(Ycx + rb + cb);
    hf[c * 2]     = *(const float4*)(h + rb + cb);
    hf[c * 2 + 1] = *(const float4*)(h + rb + cb + 4);
  }

  float s[8] = {0.f, 0.f, 0.f, 0.f, 0.f, 0.f, 0.f, 0.f};
  float tmp[8];
#pragma unroll
  for (int c = 0; c < 2; c++) {
    unpack8(q0[c], tmp);
#pragma unroll
    for (int j = 0; j < 8; j++) { s[0] += tmp[j]; s[1] += tmp[j] * tmp[j]; }
    unpack8(q1[c], tmp);
#pragma unroll
    for (int j = 0; j < 8; j++) { s[2] += tmp[j]; s[3] += tmp[j] * tmp[j]; }
    unpack8(q2[c], tmp);
#pragma unroll
    for (int j = 0; j < 8; j++) { s[4] += tmp[j]; s[5] += tmp[j] * tmp[j]; }
    unpack8(q3[c], tmp);
#pragma unroll
    for (int j = 0; j < 8; j++) { s[6] += tmp[j]; s[7] += tmp[j] * tmp[j]; }
  }
#pragma unroll
  for (int off = 1; off < 64; off <<= 1) {
#pragma unroll
    for (int q = 0; q < 8; q++) s[q] += __shfl_xor(s[q], off, 64);
  }

  const float inv = 1.0f / 1024.0f;
  const float mu0 = s[0] * inv, rs0 = rsqrtf(s[1] * inv - mu0 * mu0 + 1e-5f);
  const float mu1 = s[2] * inv, rs1 = rsqrtf(s[3] * inv - mu1 * mu1 + 1e-5f);
  const float mu2 = s[4] * inv, rs2 = rsqrtf(s[5] * inv - mu2 * mu2 + 1e-5f);
  const float mu3 = s[6] * inv, rs3 = rsqrtf(s[7] * inv - mu3 * mu3 + 1e-5f);

#pragma unroll
  for (int c = 0; c < 2; c++) {
    const int cb = c * 512 + lane * 8;
    float v0[8], v1[8], v2[8], v3[8];
    unpack8(q0[c], v0); unpack8(q1[c], v1); unpack8(q2[c], v2); unpack8(q3[c], v3);
    const float* hv = (const float*)&hf[c * 2];
    float o[8];
#pragma unroll
    for (int j = 0; j < 8; j++) {
      const int cc = cb + j;
      const float ln2 = (v0[j] - mu0) * rs0 * gamma[2 * 1024 + cc] + beta[2 * 1024 + cc];
      const float ln3 = (v1[j] - mu1) * rs1 * gamma[3 * 1024 + cc] + beta[3 * 1024 + cc];
      const float ln4 = (v2[j] - mu2) * rs2 * gamma[4 * 1024 + cc] + beta[4 * 1024 + cc];
      const float ln5 = (v3[j] - mu3) * rs3 * gamma[5 * 1024 + cc] + beta[5 * 1024 + cc];
      const float u  = fast_sigmoid(ln2 + ln3);
      const float cg = fast_tanh(ln4 + ln5);
      o[j] = (1.0f - u) * hv[j] + u * cg;
    }
    *(float4*)(out + rb + cb)     = *(float4*)&o[0];
    *(float4*)(out + rb + cb + 4) = *(float4*)&o[4];
  }
}

extern "C" void kernel_launch(void* const* d_in, const int* in_sizes, int n_in,
                              void* d_out, int out_size, void* d_ws, size_t ws_size,
                              hipStream_t stream) {
  const float* x  = (const float*)d_in[0];
  const float* h  = (const float*)d_in[1];
  const float* W_r = (const float*)d_in[2];
  const float* U_r = (const float*)d_in[3];
  const float* W_u = (const float*)d_in[4];
  const float* U_u = (const float*)d_in[5];
  const float* W_c = (const float*)d_in[6];
  const float* U_c = (const float*)d_in[7];
  const float* gamma = (const float*)d_in[8];
  const float* beta  = (const float*)d_in[9];
  float* out = (float*)d_out;

  char* ws = (char*)d_ws;
  const size_t MB = 1024 * 1024;

  u8* x8  = (u8*)(ws);                        // 8 MiB
  u8* h8  = (u8*)(ws + 8 * MB);               // 8 MiB
  u8* hr8 = (u8*)(ws + 16 * MB);              // 8 MiB
  u8* w8[6];
  for (int i = 0; i < 6; i++) w8[i] = (u8*)(ws + 24 * MB + i * MB);  // 6 MiB
  u16* Y0 = (u16*)(ws + 32 * MB);             // r_hidden -> c_hidden (reused)
  u16* Y1 = (u16*)(ws + 48 * MB);             // r_input (dead after rgate)
  u16* Y2 = (u16*)(ws + 64 * MB);             // u_hidden
  u16* Y3 = (u16*)(ws + 80 * MB);             // u_input
  u16* Y5 = (u16*)(ws + 96 * MB);             // c_input
  // total ws: 112 MiB

  // 1) fused convert: x,h -> fp8; 6 weights -> fp8 x2^13  (16384 + 6144 blocks)
  ConvArgs3 ca = {};
  ca.x = x; ca.h = h;
  ca.w[0] = W_r; ca.w[1] = U_r; ca.w[2] = W_u; ca.w[3] = U_u; ca.w[4] = W_c; ca.w[5] = U_c;
  ca.x8 = x8; ca.h8 = h8;
  for (int i = 0; i < 6; i++) ca.w8[i] = w8[i];
  convert_all<<<22528, 256, 0, stream>>>(ca);

  // 2) fp8 GEMMs, pre-rgate gates: r_h, r_x, u_x, c_x  (512 blocks = 2 CU-rounds)
  GemmF8 gA = {};
  gA.A[0] = h8; gA.Bw[0] = w8[0]; gA.Y[0] = Y0;   // r_h = h@W_r^T
  gA.A[1] = x8; gA.Bw[1] = w8[1]; gA.Y[1] = Y1;   // r_x = x@U_r^T
  gA.A[2] = x8; gA.Bw[2] = w8[3]; gA.Y[2] = Y3;   // u_x = x@U_u^T
  gA.A[3] = x8; gA.Bw[3] = w8[5]; gA.Y[3] = Y5;   // c_x = x@U_c^T
  gemm_fp8<4><<<512, 512, 0, stream>>>(gA);

  // 3) r gate: hr = h * sigmoid(LN(r_h)+LN(r_x)), written as fp8
  rgate_kernel<<<2048, 256, 0, stream>>>(Y0, Y1, h, gamma, beta, hr8);

  // 4) fp8 GEMMs, post-rgate gates: u_h, c_h  (256 blocks = 1 CU-round)
  GemmF8 gB = {};
  gB.A[0] = h8;  gB.Bw[0] = w8[2]; gB.Y[0] = Y2;  // u_h = h@W_u^T
  gB.A[1] = hr8; gB.Bw[1] = w8[4]; gB.Y[1] = Y0;  // c_h = hr@W_c^T (Y0 reuse)
  gemm_fp8<2><<<256, 512, 0, stream>>>(gB);

  // 5) u, c, out (h in fp32)
  final_fuse<<<2048, 256, 0, stream>>>(Y2, Y3, Y0, Y5, h, gamma, beta, out);
}